// Round 7
// baseline (8260.715 us; speedup 1.0000x reference)
//
#include <hip/hip_runtime.h>
#include <hip/hip_bf16.h>

// T=512, B=64, D=1024, H=1024, 4H=4096
// Pass 0: pack Wi -> split-bf16 (hi/lo) in MFMA B-fragment order (ws, 16MB)
// Pass 1: G2 = x @ Wi + b via split-bf16 MFMA, stored in SCAN-NATIVE layout:
//         G2[((step*256 + wg)*4 + gate)*256 + b*4 + u]  (bf16)
// Pass 2: cooperative scan, 256 WGs x 4 hidden units, split-bf16 MFMA,
//         flag-array barrier. h publish = sc1 (IF$-direct) stores; h read =
//         PLAIN CACHED loads after an agent-scope acquire fence (buffer_inv)
//         -> each XCD's L2 fetches h once/step, 32 WGs share it (16x dedup
//         of the IF$ broadcast that dominated round 5).

typedef __attribute__((ext_vector_type(8))) short bf16x8;
typedef __attribute__((ext_vector_type(8))) unsigned short ushx8;
typedef __attribute__((ext_vector_type(4))) unsigned short ushx4;
typedef __attribute__((ext_vector_type(4))) float f32x4;

static __device__ __forceinline__ unsigned short f2bf(float x) {
    __hip_bfloat16 h = __float2bfloat16(x);
    return __builtin_bit_cast(unsigned short, h);
}
static __device__ __forceinline__ float bf2f(unsigned short u) {
    __hip_bfloat16 h = __builtin_bit_cast(__hip_bfloat16, u);
    return __bfloat162float(h);
}

static __device__ __forceinline__ void gl_lds16(const void* g, void* l) {
    __builtin_amdgcn_global_load_lds(
        (const __attribute__((address_space(1))) unsigned int*)g,
        (__attribute__((address_space(3))) unsigned int*)l, 16, 0, 0);
}

static __device__ __forceinline__ float sigm_fast(float x) {
    return 1.f / (1.f + __expf(-x));
}
static __device__ __forceinline__ float tanh_fast(float x) {
    float e = __expf(2.f * x);
    return 1.f - 2.f / (e + 1.f);
}

// ---------------------------------------------------------------------------
// Pass 0: pack Wi[1024][4096] f32 -> WiHi/WiLo bf16 in B-fragment order.
// ---------------------------------------------------------------------------
__global__ __launch_bounds__(256)
void wi_pack(const float* __restrict__ Wi, unsigned short* __restrict__ WiHi,
             unsigned short* __restrict__ WiLo)
{
    const int bid = blockIdx.x;            // 1024 = tn(32) x kb(32)
    const int tn = bid >> 5, kb = bid & 31;
    const int t = threadIdx.x;
    const int c = t & 127, ko = t >> 7;
    const float* src = Wi + (size_t)(kb * 32 + ko * 16) * 4096 + tn * 128 + c;
    const size_t dbase = ((size_t)(tn * 32 + kb)) * 4096 + c * 8;
#pragma unroll
    for (int o = 0; o < 2; ++o) {
        ushx8 hv, lv;
#pragma unroll
        for (int q = 0; q < 8; ++q) {
            float v = src[(size_t)(o * 8 + q) * 4096];
            unsigned short h = f2bf(v);
            hv[q] = h; lv[q] = f2bf(v - bf2f(h));
        }
        int kq = ko * 2 + o;
        *(ushx8*)(WiHi + dbase + kq * 1024) = hv;
        *(ushx8*)(WiLo + dbase + kq * 1024) = lv;
    }
}

// ---------------------------------------------------------------------------
// Pass 1: G2 = x @ Wi + bias, split-bf16 MFMA, 128x128 tile, BK=32, 4 waves.
// ---------------------------------------------------------------------------
__global__ __launch_bounds__(256)
void xwi_gemm_mfma(const float* __restrict__ x,
                   const unsigned short* __restrict__ WiHi,
                   const unsigned short* __restrict__ WiLo,
                   const float* __restrict__ bias,
                   unsigned short* __restrict__ G2)
{
    __shared__ __align__(16) unsigned short AHi[4096], ALo[4096];
    __shared__ __align__(16) unsigned short BHi[4096], BLo[4096];
    const int bid = blockIdx.x;
    const int bm = bid >> 5, bn = bid & 31;
    const int m0 = bm << 7, n0 = bn << 7;
    const int t = threadIdx.x;
    const int w = t >> 6, l = t & 63, lq = l >> 4, lc = l & 15;
    const int wm = w >> 1, wn = w & 1;

    f32x4 acc[4][4] = {};
    const int row = t >> 1, kh = t & 1;
    const float* xrow = x + (size_t)(m0 + row) * 1024 + kh * 16;
    const unsigned short* bHsl = WiHi + (size_t)(bn * 32) * 4096;
    const unsigned short* bLsl = WiLo + (size_t)(bn * 32) * 4096;

    for (int kb = 0; kb < 32; ++kb) {
        float4 f0 = *(const float4*)(xrow + kb * 32 + 0);
        float4 f1 = *(const float4*)(xrow + kb * 32 + 4);
        float4 f2 = *(const float4*)(xrow + kb * 32 + 8);
        float4 f3 = *(const float4*)(xrow + kb * 32 + 12);
        float fs[16] = {f0.x, f0.y, f0.z, f0.w, f1.x, f1.y, f1.z, f1.w,
                        f2.x, f2.y, f2.z, f2.w, f3.x, f3.y, f3.z, f3.w};
#pragma unroll
        for (int o = 0; o < 2; ++o) {
            ushx8 hv, lv;
#pragma unroll
            for (int q = 0; q < 8; ++q) {
                float v = fs[o * 8 + q];
                unsigned short h = f2bf(v);
                hv[q] = h; lv[q] = f2bf(v - bf2f(h));
            }
            int kq = kh * 2 + o;
            *(ushx8*)&AHi[kq * 1024 + row * 8] = hv;
            *(ushx8*)&ALo[kq * 1024 + row * 8] = lv;
        }
        {
            const unsigned short* sH = bHsl + (size_t)kb * 4096;
            const unsigned short* sL = bLsl + (size_t)kb * 4096;
            gl_lds16(sH + (size_t)(w * 128 + l) * 8,      &BHi[(w * 128) * 8]);
            gl_lds16(sH + (size_t)(w * 128 + 64 + l) * 8, &BHi[(w * 128 + 64) * 8]);
            gl_lds16(sL + (size_t)(w * 128 + l) * 8,      &BLo[(w * 128) * 8]);
            gl_lds16(sL + (size_t)(w * 128 + 64 + l) * 8, &BLo[(w * 128 + 64) * 8]);
        }
        __syncthreads();

        bf16x8 xh[4], xl[4], wh_[4], wl_[4];
#pragma unroll
        for (int a = 0; a < 4; ++a) {
            int off = lq * 1024 + (wm * 64 + a * 16 + lc) * 8;
            xh[a] = *(const bf16x8*)&AHi[off];
            xl[a] = *(const bf16x8*)&ALo[off];
        }
#pragma unroll
        for (int b = 0; b < 4; ++b) {
            int off = lq * 1024 + (wn * 64 + b * 16 + lc) * 8;
            wh_[b] = *(const bf16x8*)&BHi[off];
            wl_[b] = *(const bf16x8*)&BLo[off];
        }
#pragma unroll
        for (int a = 0; a < 4; ++a)
#pragma unroll
            for (int b = 0; b < 4; ++b) {
                acc[a][b] = __builtin_amdgcn_mfma_f32_16x16x32_bf16(wh_[b], xh[a], acc[a][b], 0, 0, 0);
                acc[a][b] = __builtin_amdgcn_mfma_f32_16x16x32_bf16(wl_[b], xh[a], acc[a][b], 0, 0, 0);
                acc[a][b] = __builtin_amdgcn_mfma_f32_16x16x32_bf16(wh_[b], xl[a], acc[a][b], 0, 0, 0);
            }
        __syncthreads();
    }

    float bv[4][4];
#pragma unroll
    for (int b = 0; b < 4; ++b)
#pragma unroll
        for (int r = 0; r < 4; ++r)
            bv[b][r] = bias[n0 + wn * 64 + b * 16 + lq * 4 + r];
#pragma unroll
    for (int a = 0; a < 4; ++a) {
        int m = m0 + wm * 64 + a * 16 + lc;
        int step = m >> 6, b_el = m & 63;
#pragma unroll
        for (int b = 0; b < 4; ++b) {
            int j_abs = n0 + wn * 64 + b * 16 + lq * 4;
            int gate = j_abs >> 10;
            int wg_t = (j_abs & 1023) >> 2;
            ushx4 sv;
#pragma unroll
            for (int r = 0; r < 4; ++r) sv[r] = f2bf(acc[a][b][r] + bv[b][r]);
            *(ushx4*)(G2 + (((size_t)(step * 256 + wg_t) * 4 + gate) * 256 + b_el * 4)) = sv;
        }
    }
}

// ---------------------------------------------------------------------------
// Pass 2: cooperative MFMA scan. 256 WGs x 256 threads (4 waves), 4 units/WG.
// h read path: plain cached 16B loads, made coherent by an agent-scope
// acquire fence (buffer_inv) after each barrier poll.
// ---------------------------------------------------------------------------
__global__ __launch_bounds__(256, 1)
void lstm_scan_mfma(const unsigned short* __restrict__ G2,
                    const float* __restrict__ Wh,
                    const float* __restrict__ h0, const float* __restrict__ c0,
                    float* __restrict__ out,
                    unsigned int* __restrict__ hp0, unsigned int* __restrict__ lp0,
                    unsigned int* __restrict__ hp1, unsigned int* __restrict__ lp1,
                    unsigned int* __restrict__ flags)
{
    __shared__ __align__(16) unsigned short WhHiS[16384];  // 32 KB
    __shared__ __align__(16) unsigned short WhLoS[16384];  // 32 KB
    __shared__ float zS[64 * 20];

    const int t  = threadIdx.x;
    const int wg = blockIdx.x;           // 0..255
    const int w  = t >> 6;
    const int l  = t & 63;
    const int lq = l >> 4, lc = l & 15;

    // Wh slice -> LDS (once): 16 z-cols, hi/lo split, B-fragment order
    for (int idx = t; idx < 16384; idx += 256) {
        int k = idx >> 4, c = idx & 15;
        int gcol = (c >> 2) * 1024 + wg * 4 + (c & 3);
        float wv = Wh[(size_t)k * 4096 + gcol];
        unsigned short hi = f2bf(wv);
        unsigned short lo = f2bf(wv - bf2f(hi));
        int pos = (((k >> 5) * 64) + (((k >> 3) & 3) * 16 + c)) * 8 + (k & 7);
        WhHiS[pos] = hi; WhLoS[pos] = lo;
    }

    // init hpack buffer 0 from h0 (sc1 stores -> IF$)
    {
        int idx = wg * 256 + t;
        if (idx < 32768) {
            int b = idx >> 9, k = (idx & 511) * 2;
            float v0 = h0[b * 1024 + k], v1 = h0[b * 1024 + k + 1];
            unsigned short h0s = f2bf(v0), h1s = f2bf(v1);
            unsigned short l0s = f2bf(v0 - bf2f(h0s)), l1s = f2bf(v1 - bf2f(h1s));
            int p32 = ((k >> 3) * 64 + b) * 4 + ((k & 7) >> 1);
            __hip_atomic_store(hp0 + p32, (unsigned int)h0s | ((unsigned int)h1s << 16),
                               __ATOMIC_RELAXED, __HIP_MEMORY_SCOPE_AGENT);
            __hip_atomic_store(lp0 + p32, (unsigned int)l0s | ((unsigned int)l1s << 16),
                               __ATOMIC_RELAXED, __HIP_MEMORY_SCOPE_AGENT);
        }
    }

    const int b_el = t >> 2, u_el = t & 3;
    const int j = wg * 4 + u_el;
    float c_state = c0[b_el * 1024 + j];

    // initial barrier (+ acquire fence so plain h loads see the sc1 init)
    {
        asm volatile("s_waitcnt vmcnt(0)" ::: "memory");
        __syncthreads();
        if (t == 0)
            __hip_atomic_store(&flags[wg * 32], 1u, __ATOMIC_RELAXED,
                               __HIP_MEMORY_SCOPE_AGENT);
        while (__hip_atomic_load(&flags[t * 32], __ATOMIC_RELAXED,
                                 __HIP_MEMORY_SCOPE_AGENT) < 1u) {}
        __syncthreads();
        __builtin_amdgcn_fence(__ATOMIC_ACQUIRE, "agent");
    }

    const int arow = (w << 4) + lc;
    for (int step = 0; step < 512; ++step) {
        const unsigned short* hH =
            (const unsigned short*)((step & 1) ? hp1 : hp0);
        const unsigned short* hL =
            (const unsigned short*)((step & 1) ? lp1 : lp0);
        unsigned int* nH = (step & 1) ? hp0 : hp1;
        unsigned int* nL = (step & 1) ? lp0 : lp1;

        // G prefetch: contiguous 2KB/WG panel, 4 x 2B per thread (dense)
        size_t pb = ((size_t)(step * 256 + wg) * 4) * 256 + t;
        unsigned short gvi = G2[pb];
        unsigned short gvf = G2[pb + 256];
        unsigned short gvg = G2[pb + 512];
        unsigned short gvo = G2[pb + 768];

        f32x4 acc0 = {0.f, 0.f, 0.f, 0.f};
        f32x4 acc1 = {0.f, 0.f, 0.f, 0.f};
        f32x4 acc2 = {0.f, 0.f, 0.f, 0.f};

        // software-pipelined K loop: 4 groups of 8 kb, double-buffered regs
        bf16x8 ah[2][8], al[2][8];
#pragma unroll
        for (int i = 0; i < 8; ++i) {
            int apos = ((i * 4 + lq) * 64 + arow) * 8;
            ah[0][i] = *(const bf16x8*)(hH + apos);
            al[0][i] = *(const bf16x8*)(hL + apos);
        }
#pragma unroll
        for (int g4 = 0; g4 < 4; ++g4) {
            if (g4 < 3) {
#pragma unroll
                for (int i = 0; i < 8; ++i) {
                    int kb = (g4 + 1) * 8 + i;
                    int apos = ((kb * 4 + lq) * 64 + arow) * 8;
                    ah[(g4 + 1) & 1][i] = *(const bf16x8*)(hH + apos);
                    al[(g4 + 1) & 1][i] = *(const bf16x8*)(hL + apos);
                }
            }
#pragma unroll
            for (int i = 0; i < 8; ++i) {
                int kb = g4 * 8 + i;
                int bpos = (kb * 64 + l) * 8;
                bf16x8 bh = *(const bf16x8*)&WhHiS[bpos];
                bf16x8 bl = *(const bf16x8*)&WhLoS[bpos];
                bf16x8 a_h = ah[g4 & 1][i];
                bf16x8 a_l = al[g4 & 1][i];
                acc0 = __builtin_amdgcn_mfma_f32_16x16x32_bf16(a_h, bh, acc0, 0, 0, 0);
                acc1 = __builtin_amdgcn_mfma_f32_16x16x32_bf16(a_l, bh, acc1, 0, 0, 0);
                acc2 = __builtin_amdgcn_mfma_f32_16x16x32_bf16(a_h, bl, acc2, 0, 0, 0);
            }
        }

        // z tile -> LDS transpose (stride 20: <=2-way banks, free)
#pragma unroll
        for (int r = 0; r < 4; ++r)
            zS[(w * 16 + lq * 4 + r) * 20 + lc] = acc0[r] + acc1[r] + acc2[r];
        __syncthreads();

        float zi = bf2f(gvi) + zS[b_el * 20 + u_el];
        float zf = bf2f(gvf) + zS[b_el * 20 + 4 + u_el];
        float zg = bf2f(gvg) + zS[b_el * 20 + 8 + u_el];
        float zo = bf2f(gvo) + zS[b_el * 20 + 12 + u_el];

        float ig = sigm_fast(zi);
        float fg = sigm_fast(zf);
        float gg = tanh_fast(zg);
        float og = sigm_fast(zo);

        c_state = fg * c_state + ig * gg;
        float nh = og * tanh_fast(c_state);

        // publish h (sc1 -> IF$, packed pairs via shfl)
        unsigned int hiw = f2bf(nh);
        unsigned int low = f2bf(nh - bf2f((unsigned short)hiw));
        unsigned int hi_o = (unsigned int)__shfl_xor((int)hiw, 1);
        unsigned int lo_o = (unsigned int)__shfl_xor((int)low, 1);
        if ((t & 1) == 0) {
            int p32 = ((j >> 3) * 64 + b_el) * 4 + ((j & 7) >> 1);
            __hip_atomic_store(nH + p32, (hiw & 0xffffu) | (hi_o << 16),
                               __ATOMIC_RELAXED, __HIP_MEMORY_SCOPE_AGENT);
            __hip_atomic_store(nL + p32, (low & 0xffffu) | (lo_o << 16),
                               __ATOMIC_RELAXED, __HIP_MEMORY_SCOPE_AGENT);
        }

        // barrier: arrive (publishes drained), deferred out store, poll,
        // then acquire fence (buffer_inv) so next step's plain h loads are
        // coherent with all WGs' sc1 publishes.
        asm volatile("s_waitcnt vmcnt(0)" ::: "memory");
        __syncthreads();
        unsigned int target = (unsigned int)(step + 2);
        if (t == 0)
            __hip_atomic_store(&flags[wg * 32], target, __ATOMIC_RELAXED,
                               __HIP_MEMORY_SCOPE_AGENT);
        out[(size_t)step * 65536 + b_el * 1024 + j] = nh;   // drains next step
        while (__hip_atomic_load(&flags[t * 32], __ATOMIC_RELAXED,
                                 __HIP_MEMORY_SCOPE_AGENT) < target) {}
        __syncthreads();
        __builtin_amdgcn_fence(__ATOMIC_ACQUIRE, "agent");
    }
}

// ---------------------------------------------------------------------------
extern "C" void kernel_launch(void* const* d_in, const int* in_sizes, int n_in,
                              void* d_out, int out_size, void* d_ws, size_t ws_size,
                              hipStream_t stream)
{
    const float* x  = (const float*)d_in[0];
    const float* h0 = (const float*)d_in[1];
    const float* c0 = (const float*)d_in[2];
    const float* Wi = (const float*)d_in[3];
    const float* Wh = (const float*)d_in[4];
    const float* bb = (const float*)d_in[5];
    float* out = (float*)d_out;

    // ws layout: 4 hpack (128KB each) | flags 16KB | WiHi 8MB | WiLo 8MB | G2 268MB
    unsigned int* hp0 = (unsigned int*)d_ws;
    unsigned int* lp0 = hp0 + 32768;
    unsigned int* hp1 = lp0 + 32768;
    unsigned int* lp1 = hp1 + 32768;
    unsigned int* flags = lp1 + 32768;
    unsigned short* WiHi = (unsigned short*)(flags + 4096);
    unsigned short* WiLo = WiHi + 4194304;
    unsigned short* G2 = WiLo + 4194304;

    hipMemsetAsync(flags, 0, 4096 * sizeof(unsigned int), stream);
    wi_pack<<<dim3(1024), dim3(256), 0, stream>>>(Wi, WiHi, WiLo);
    xwi_gemm_mfma<<<dim3(8192), dim3(256), 0, stream>>>(x, WiHi, WiLo, bb, G2);

    void* args[] = {(void*)&G2, (void*)&Wh, (void*)&h0, (void*)&c0, (void*)&out,
                    (void*)&hp0, (void*)&lp0, (void*)&hp1, (void*)&lp1,
                    (void*)&flags};
    hipLaunchCooperativeKernel(reinterpret_cast<void*>(&lstm_scan_mfma),
                               dim3(256), dim3(256), args, 0, stream);
}

// Round 8
// 5228.055 us; speedup vs baseline: 1.5801x; 1.5801x over previous
//
#include <hip/hip_runtime.h>
#include <hip/hip_bf16.h>

// T=512, B=64, D=1024, H=1024, 4H=4096
// Pass 0: pack Wi -> split-bf16 (hi/lo) in MFMA B-fragment order (ws, 16MB)
// Pass 1: G2 = x @ Wi + b via split-bf16 MFMA, stored in SCAN-NATIVE layout:
//         G2[((step*256 + wg)*4 + gate)*256 + b*4 + u]  (bf16)
// Pass 2: cooperative scan, 256 WGs x 4 hidden units, MFMA z = G + h @ Wh.
//         h broadcast: bf16 (hi-only) via sc1/IF$ — round-8 change; Wh stays
//         split hi/lo in LDS. Dense-flag barrier, wave-0-only poll.

typedef __attribute__((ext_vector_type(8))) short bf16x8;
typedef __attribute__((ext_vector_type(8))) unsigned short ushx8;
typedef __attribute__((ext_vector_type(4))) unsigned short ushx4;
typedef __attribute__((ext_vector_type(4))) float f32x4;
typedef __attribute__((ext_vector_type(2))) unsigned long long u64x2;

static __device__ __forceinline__ unsigned short f2bf(float x) {
    __hip_bfloat16 h = __float2bfloat16(x);
    return __builtin_bit_cast(unsigned short, h);
}
static __device__ __forceinline__ float bf2f(unsigned short u) {
    __hip_bfloat16 h = __builtin_bit_cast(__hip_bfloat16, u);
    return __bfloat162float(h);
}

// coherent (agent-scope, L2-bypassing) 16B load as 2 x u64 relaxed atomics
static __device__ __forceinline__ bf16x8 ld_h16(const unsigned long long* p) {
    unsigned long long a = __hip_atomic_load(p,     __ATOMIC_RELAXED, __HIP_MEMORY_SCOPE_AGENT);
    unsigned long long b = __hip_atomic_load(p + 1, __ATOMIC_RELAXED, __HIP_MEMORY_SCOPE_AGENT);
    u64x2 v; v.x = a; v.y = b;
    return __builtin_bit_cast(bf16x8, v);
}

static __device__ __forceinline__ void gl_lds16(const void* g, void* l) {
    __builtin_amdgcn_global_load_lds(
        (const __attribute__((address_space(1))) unsigned int*)g,
        (__attribute__((address_space(3))) unsigned int*)l, 16, 0, 0);
}

static __device__ __forceinline__ float sigm_fast(float x) {
    return 1.f / (1.f + __expf(-x));
}
static __device__ __forceinline__ float tanh_fast(float x) {
    float e = __expf(2.f * x);
    return 1.f - 2.f / (e + 1.f);
}

// ---------------------------------------------------------------------------
// Pass 0: pack Wi[1024][4096] f32 -> WiHi/WiLo bf16 in B-fragment order.
// ---------------------------------------------------------------------------
__global__ __launch_bounds__(256)
void wi_pack(const float* __restrict__ Wi, unsigned short* __restrict__ WiHi,
             unsigned short* __restrict__ WiLo)
{
    const int bid = blockIdx.x;            // 1024 = tn(32) x kb(32)
    const int tn = bid >> 5, kb = bid & 31;
    const int t = threadIdx.x;
    const int c = t & 127, ko = t >> 7;
    const float* src = Wi + (size_t)(kb * 32 + ko * 16) * 4096 + tn * 128 + c;
    const size_t dbase = ((size_t)(tn * 32 + kb)) * 4096 + c * 8;
#pragma unroll
    for (int o = 0; o < 2; ++o) {
        ushx8 hv, lv;
#pragma unroll
        for (int q = 0; q < 8; ++q) {
            float v = src[(size_t)(o * 8 + q) * 4096];
            unsigned short h = f2bf(v);
            hv[q] = h; lv[q] = f2bf(v - bf2f(h));
        }
        int kq = ko * 2 + o;
        *(ushx8*)(WiHi + dbase + kq * 1024) = hv;
        *(ushx8*)(WiLo + dbase + kq * 1024) = lv;
    }
}

// ---------------------------------------------------------------------------
// Pass 1: G2 = x @ Wi + bias, split-bf16 MFMA, 128x128 tile, BK=32, 4 waves.
// ---------------------------------------------------------------------------
__global__ __launch_bounds__(256)
void xwi_gemm_mfma(const float* __restrict__ x,
                   const unsigned short* __restrict__ WiHi,
                   const unsigned short* __restrict__ WiLo,
                   const float* __restrict__ bias,
                   unsigned short* __restrict__ G2)
{
    __shared__ __align__(16) unsigned short AHi[4096], ALo[4096];
    __shared__ __align__(16) unsigned short BHi[4096], BLo[4096];
    const int bid = blockIdx.x;
    const int bm = bid >> 5, bn = bid & 31;
    const int m0 = bm << 7, n0 = bn << 7;
    const int t = threadIdx.x;
    const int w = t >> 6, l = t & 63, lq = l >> 4, lc = l & 15;
    const int wm = w >> 1, wn = w & 1;

    f32x4 acc[4][4] = {};
    const int row = t >> 1, kh = t & 1;
    const float* xrow = x + (size_t)(m0 + row) * 1024 + kh * 16;
    const unsigned short* bHsl = WiHi + (size_t)(bn * 32) * 4096;
    const unsigned short* bLsl = WiLo + (size_t)(bn * 32) * 4096;

    for (int kb = 0; kb < 32; ++kb) {
        float4 f0 = *(const float4*)(xrow + kb * 32 + 0);
        float4 f1 = *(const float4*)(xrow + kb * 32 + 4);
        float4 f2 = *(const float4*)(xrow + kb * 32 + 8);
        float4 f3 = *(const float4*)(xrow + kb * 32 + 12);
        float fs[16] = {f0.x, f0.y, f0.z, f0.w, f1.x, f1.y, f1.z, f1.w,
                        f2.x, f2.y, f2.z, f2.w, f3.x, f3.y, f3.z, f3.w};
#pragma unroll
        for (int o = 0; o < 2; ++o) {
            ushx8 hv, lv;
#pragma unroll
            for (int q = 0; q < 8; ++q) {
                float v = fs[o * 8 + q];
                unsigned short h = f2bf(v);
                hv[q] = h; lv[q] = f2bf(v - bf2f(h));
            }
            int kq = kh * 2 + o;
            *(ushx8*)&AHi[kq * 1024 + row * 8] = hv;
            *(ushx8*)&ALo[kq * 1024 + row * 8] = lv;
        }
        {
            const unsigned short* sH = bHsl + (size_t)kb * 4096;
            const unsigned short* sL = bLsl + (size_t)kb * 4096;
            gl_lds16(sH + (size_t)(w * 128 + l) * 8,      &BHi[(w * 128) * 8]);
            gl_lds16(sH + (size_t)(w * 128 + 64 + l) * 8, &BHi[(w * 128 + 64) * 8]);
            gl_lds16(sL + (size_t)(w * 128 + l) * 8,      &BLo[(w * 128) * 8]);
            gl_lds16(sL + (size_t)(w * 128 + 64 + l) * 8, &BLo[(w * 128 + 64) * 8]);
        }
        __syncthreads();

        bf16x8 xh[4], xl[4], wh_[4], wl_[4];
#pragma unroll
        for (int a = 0; a < 4; ++a) {
            int off = lq * 1024 + (wm * 64 + a * 16 + lc) * 8;
            xh[a] = *(const bf16x8*)&AHi[off];
            xl[a] = *(const bf16x8*)&ALo[off];
        }
#pragma unroll
        for (int b = 0; b < 4; ++b) {
            int off = lq * 1024 + (wn * 64 + b * 16 + lc) * 8;
            wh_[b] = *(const bf16x8*)&BHi[off];
            wl_[b] = *(const bf16x8*)&BLo[off];
        }
#pragma unroll
        for (int a = 0; a < 4; ++a)
#pragma unroll
            for (int b = 0; b < 4; ++b) {
                acc[a][b] = __builtin_amdgcn_mfma_f32_16x16x32_bf16(wh_[b], xh[a], acc[a][b], 0, 0, 0);
                acc[a][b] = __builtin_amdgcn_mfma_f32_16x16x32_bf16(wl_[b], xh[a], acc[a][b], 0, 0, 0);
                acc[a][b] = __builtin_amdgcn_mfma_f32_16x16x32_bf16(wh_[b], xl[a], acc[a][b], 0, 0, 0);
            }
        __syncthreads();
    }

    float bv[4][4];
#pragma unroll
    for (int b = 0; b < 4; ++b)
#pragma unroll
        for (int r = 0; r < 4; ++r)
            bv[b][r] = bias[n0 + wn * 64 + b * 16 + lq * 4 + r];
#pragma unroll
    for (int a = 0; a < 4; ++a) {
        int m = m0 + wm * 64 + a * 16 + lc;
        int step = m >> 6, b_el = m & 63;
#pragma unroll
        for (int b = 0; b < 4; ++b) {
            int j_abs = n0 + wn * 64 + b * 16 + lq * 4;
            int gate = j_abs >> 10;
            int wg_t = (j_abs & 1023) >> 2;
            ushx4 sv;
#pragma unroll
            for (int r = 0; r < 4; ++r) sv[r] = f2bf(acc[a][b][r] + bv[b][r]);
            *(ushx4*)(G2 + (((size_t)(step * 256 + wg_t) * 4 + gate) * 256 + b_el * 4)) = sv;
        }
    }
}

// ---------------------------------------------------------------------------
// Pass 2: cooperative MFMA scan. 256 WGs x 256 threads (4 waves), 4 units/WG.
// Round-5 structure (sc1 h path, no fences). Round-8 changes: h is bf16
// hi-only (half the IF$ broadcast, 2 MFMAs/kb), dense flags + wave0-only
// poll, last-step barrier skip.
// ---------------------------------------------------------------------------
__global__ __launch_bounds__(256, 1)
void lstm_scan_mfma(const unsigned short* __restrict__ G2,
                    const float* __restrict__ Wh,
                    const float* __restrict__ h0, const float* __restrict__ c0,
                    float* __restrict__ out,
                    unsigned int* __restrict__ hp0,
                    unsigned int* __restrict__ hp1,
                    unsigned int* __restrict__ flags)
{
    __shared__ __align__(16) unsigned short WhHiS[16384];  // 32 KB
    __shared__ __align__(16) unsigned short WhLoS[16384];  // 32 KB
    __shared__ float zS[64 * 20];

    const int t  = threadIdx.x;
    const int wg = blockIdx.x;           // 0..255
    const int w  = t >> 6;
    const int l  = t & 63;
    const int lq = l >> 4, lc = l & 15;

    // Wh slice -> LDS (once): 16 z-cols, hi/lo split, B-fragment order
    for (int idx = t; idx < 16384; idx += 256) {
        int k = idx >> 4, c = idx & 15;
        int gcol = (c >> 2) * 1024 + wg * 4 + (c & 3);
        float wv = Wh[(size_t)k * 4096 + gcol];
        unsigned short hi = f2bf(wv);
        unsigned short lo = f2bf(wv - bf2f(hi));
        int pos = (((k >> 5) * 64) + (((k >> 3) & 3) * 16 + c)) * 8 + (k & 7);
        WhHiS[pos] = hi; WhLoS[pos] = lo;
    }

    // init hpack buffer 0 from h0 (bf16 hi only, sc1 -> IF$)
    {
        int idx = wg * 256 + t;
        if (idx < 32768) {
            int b = idx >> 9, k = (idx & 511) * 2;
            unsigned short h0s = f2bf(h0[b * 1024 + k]);
            unsigned short h1s = f2bf(h0[b * 1024 + k + 1]);
            int p32 = ((k >> 3) * 64 + b) * 4 + ((k & 7) >> 1);
            __hip_atomic_store(hp0 + p32, (unsigned int)h0s | ((unsigned int)h1s << 16),
                               __ATOMIC_RELAXED, __HIP_MEMORY_SCOPE_AGENT);
        }
    }

    const int b_el = t >> 2, u_el = t & 3;
    const int j = wg * 4 + u_el;
    float c_state = c0[b_el * 1024 + j];

    // initial barrier (dense flags, wave0 poll)
    {
        asm volatile("s_waitcnt vmcnt(0)" ::: "memory");
        __syncthreads();
        if (t == 0)
            __hip_atomic_store(&flags[wg], 1u, __ATOMIC_RELAXED,
                               __HIP_MEMORY_SCOPE_AGENT);
        if (t < 64) {
            const unsigned int* f4 = flags + t * 4;
            for (;;) {
                unsigned int a = __hip_atomic_load(f4 + 0, __ATOMIC_RELAXED, __HIP_MEMORY_SCOPE_AGENT);
                unsigned int b = __hip_atomic_load(f4 + 1, __ATOMIC_RELAXED, __HIP_MEMORY_SCOPE_AGENT);
                unsigned int c = __hip_atomic_load(f4 + 2, __ATOMIC_RELAXED, __HIP_MEMORY_SCOPE_AGENT);
                unsigned int d = __hip_atomic_load(f4 + 3, __ATOMIC_RELAXED, __HIP_MEMORY_SCOPE_AGENT);
                if (a >= 1u && b >= 1u && c >= 1u && d >= 1u) break;
            }
        }
        __syncthreads();
        asm volatile("" ::: "memory");
    }

    const int arow = (w << 4) + lc;
    for (int step = 0; step < 512; ++step) {
        const unsigned long long* hH =
            (const unsigned long long*)((step & 1) ? hp1 : hp0);
        unsigned int* nH = (step & 1) ? hp0 : hp1;

        // G prefetch: contiguous 2KB/WG panel, 4 x 2B per thread (dense)
        size_t pb = ((size_t)(step * 256 + wg) * 4) * 256 + t;
        unsigned short gvi = G2[pb];
        unsigned short gvf = G2[pb + 256];
        unsigned short gvg = G2[pb + 512];
        unsigned short gvo = G2[pb + 768];

        f32x4 acc0 = {0.f, 0.f, 0.f, 0.f};
        f32x4 acc2 = {0.f, 0.f, 0.f, 0.f};

        // software-pipelined K loop: 4 groups of 8 kb, double-buffered regs
        bf16x8 ah[2][8];
#pragma unroll
        for (int i = 0; i < 8; ++i) {
            int a64 = ((i * 4 + lq) * 64 + arow) * 2;
            ah[0][i] = ld_h16(hH + a64);
        }
#pragma unroll
        for (int g4 = 0; g4 < 4; ++g4) {
            if (g4 < 3) {
#pragma unroll
                for (int i = 0; i < 8; ++i) {
                    int kb = (g4 + 1) * 8 + i;
                    int a64 = ((kb * 4 + lq) * 64 + arow) * 2;
                    ah[(g4 + 1) & 1][i] = ld_h16(hH + a64);
                }
            }
#pragma unroll
            for (int i = 0; i < 8; ++i) {
                int kb = g4 * 8 + i;
                int bpos = (kb * 64 + l) * 8;
                bf16x8 bh = *(const bf16x8*)&WhHiS[bpos];
                bf16x8 bl = *(const bf16x8*)&WhLoS[bpos];
                bf16x8 a_h = ah[g4 & 1][i];
                acc0 = __builtin_amdgcn_mfma_f32_16x16x32_bf16(a_h, bh, acc0, 0, 0, 0);
                acc2 = __builtin_amdgcn_mfma_f32_16x16x32_bf16(a_h, bl, acc2, 0, 0, 0);
            }
        }

        // z tile -> LDS transpose (stride 20: <=2-way banks, free)
#pragma unroll
        for (int r = 0; r < 4; ++r)
            zS[(w * 16 + lq * 4 + r) * 20 + lc] = acc0[r] + acc2[r];
        __syncthreads();

        float zi = bf2f(gvi) + zS[b_el * 20 + u_el];
        float zf = bf2f(gvf) + zS[b_el * 20 + 4 + u_el];
        float zg = bf2f(gvg) + zS[b_el * 20 + 8 + u_el];
        float zo = bf2f(gvo) + zS[b_el * 20 + 12 + u_el];

        float ig = sigm_fast(zi);
        float fg = sigm_fast(zf);
        float gg = tanh_fast(zg);
        float og = sigm_fast(zo);

        c_state = fg * c_state + ig * gg;
        float nh = og * tanh_fast(c_state);

        if (step == 511) {
            out[(size_t)step * 65536 + b_el * 1024 + j] = nh;
            break;                      // no publish/barrier needed
        }

        // publish h (bf16 hi only, sc1 -> IF$, packed pairs via shfl)
        unsigned int hiw = f2bf(nh);
        unsigned int hi_o = (unsigned int)__shfl_xor((int)hiw, 1);
        if ((t & 1) == 0) {
            int p32 = ((j >> 3) * 64 + b_el) * 4 + ((j & 7) >> 1);
            __hip_atomic_store(nH + p32, (hiw & 0xffffu) | (hi_o << 16),
                               __ATOMIC_RELAXED, __HIP_MEMORY_SCOPE_AGENT);
        }

        // barrier: arrive (publishes drained), deferred out store, wave0 poll
        asm volatile("s_waitcnt vmcnt(0)" ::: "memory");
        __syncthreads();
        unsigned int target = (unsigned int)(step + 2);
        if (t == 0)
            __hip_atomic_store(&flags[wg], target, __ATOMIC_RELAXED,
                               __HIP_MEMORY_SCOPE_AGENT);
        out[(size_t)step * 65536 + b_el * 1024 + j] = nh;   // drains next step
        if (t < 64) {
            const unsigned int* f4 = flags + t * 4;
            for (;;) {
                unsigned int a = __hip_atomic_load(f4 + 0, __ATOMIC_RELAXED, __HIP_MEMORY_SCOPE_AGENT);
                unsigned int b = __hip_atomic_load(f4 + 1, __ATOMIC_RELAXED, __HIP_MEMORY_SCOPE_AGENT);
                unsigned int c = __hip_atomic_load(f4 + 2, __ATOMIC_RELAXED, __HIP_MEMORY_SCOPE_AGENT);
                unsigned int d = __hip_atomic_load(f4 + 3, __ATOMIC_RELAXED, __HIP_MEMORY_SCOPE_AGENT);
                if (a >= target && b >= target && c >= target && d >= target) break;
            }
        }
        __syncthreads();
        asm volatile("" ::: "memory");
    }
}

// ---------------------------------------------------------------------------
extern "C" void kernel_launch(void* const* d_in, const int* in_sizes, int n_in,
                              void* d_out, int out_size, void* d_ws, size_t ws_size,
                              hipStream_t stream)
{
    const float* x  = (const float*)d_in[0];
    const float* h0 = (const float*)d_in[1];
    const float* c0 = (const float*)d_in[2];
    const float* Wi = (const float*)d_in[3];
    const float* Wh = (const float*)d_in[4];
    const float* bb = (const float*)d_in[5];
    float* out = (float*)d_out;

    // ws layout: hp0/hp1 (128KB each) | flags 16KB | WiHi 8MB | WiLo 8MB | G2 268MB
    unsigned int* hp0 = (unsigned int*)d_ws;
    unsigned int* hp1 = hp0 + 32768;
    unsigned int* flags = hp1 + 32768;
    unsigned short* WiHi = (unsigned short*)(flags + 4096);
    unsigned short* WiLo = WiHi + 4194304;
    unsigned short* G2 = WiLo + 4194304;

    hipMemsetAsync(flags, 0, 4096 * sizeof(unsigned int), stream);
    wi_pack<<<dim3(1024), dim3(256), 0, stream>>>(Wi, WiHi, WiLo);
    xwi_gemm_mfma<<<dim3(8192), dim3(256), 0, stream>>>(x, WiHi, WiLo, bb, G2);

    void* args[] = {(void*)&G2, (void*)&Wh, (void*)&h0, (void*)&c0, (void*)&out,
                    (void*)&hp0, (void*)&hp1, (void*)&flags};
    hipLaunchCooperativeKernel(reinterpret_cast<void*>(&lstm_scan_mfma),
                               dim3(256), dim3(256), args, 0, stream);
}

// Round 9
// 3441.267 us; speedup vs baseline: 2.4005x; 1.5192x over previous
//
#include <hip/hip_runtime.h>
#include <hip/hip_bf16.h>

// T=512, B=64, D=1024, H=1024, 4H=4096
// Pass 0: pack Wi -> split-bf16 (hi/lo) in MFMA B-fragment order (ws, 16MB)
// Pass 1: G2 = x @ Wi + b via split-bf16 MFMA, stored in SCAN-NATIVE layout:
//         G2[((step*256 + wg)*4 + gate)*256 + b*4 + u]  (bf16)
// Pass 2: cooperative scan, 256 WGs x 4 hidden units, MFMA z = G + h @ Wh.
//         h broadcast bf16 hi-only via sc1/IF$; Wh split hi/lo in LDS.
//         Barrier = round-5 verified form: flags 128B apart (one line per WG,
//         no line sharing on arrival), all 256 threads poll one flag each.

typedef __attribute__((ext_vector_type(8))) short bf16x8;
typedef __attribute__((ext_vector_type(8))) unsigned short ushx8;
typedef __attribute__((ext_vector_type(4))) unsigned short ushx4;
typedef __attribute__((ext_vector_type(4))) float f32x4;
typedef __attribute__((ext_vector_type(2))) unsigned long long u64x2;

static __device__ __forceinline__ unsigned short f2bf(float x) {
    __hip_bfloat16 h = __float2bfloat16(x);
    return __builtin_bit_cast(unsigned short, h);
}
static __device__ __forceinline__ float bf2f(unsigned short u) {
    __hip_bfloat16 h = __builtin_bit_cast(__hip_bfloat16, u);
    return __bfloat162float(h);
}

// coherent (agent-scope, L2-bypassing) 16B load as 2 x u64 relaxed atomics
static __device__ __forceinline__ bf16x8 ld_h16(const unsigned long long* p) {
    unsigned long long a = __hip_atomic_load(p,     __ATOMIC_RELAXED, __HIP_MEMORY_SCOPE_AGENT);
    unsigned long long b = __hip_atomic_load(p + 1, __ATOMIC_RELAXED, __HIP_MEMORY_SCOPE_AGENT);
    u64x2 v; v.x = a; v.y = b;
    return __builtin_bit_cast(bf16x8, v);
}

static __device__ __forceinline__ void gl_lds16(const void* g, void* l) {
    __builtin_amdgcn_global_load_lds(
        (const __attribute__((address_space(1))) unsigned int*)g,
        (__attribute__((address_space(3))) unsigned int*)l, 16, 0, 0);
}

static __device__ __forceinline__ float sigm_fast(float x) {
    return 1.f / (1.f + __expf(-x));
}
static __device__ __forceinline__ float tanh_fast(float x) {
    float e = __expf(2.f * x);
    return 1.f - 2.f / (e + 1.f);
}

// ---------------------------------------------------------------------------
// Pass 0: pack Wi[1024][4096] f32 -> WiHi/WiLo bf16 in B-fragment order.
// ---------------------------------------------------------------------------
__global__ __launch_bounds__(256)
void wi_pack(const float* __restrict__ Wi, unsigned short* __restrict__ WiHi,
             unsigned short* __restrict__ WiLo)
{
    const int bid = blockIdx.x;            // 1024 = tn(32) x kb(32)
    const int tn = bid >> 5, kb = bid & 31;
    const int t = threadIdx.x;
    const int c = t & 127, ko = t >> 7;
    const float* src = Wi + (size_t)(kb * 32 + ko * 16) * 4096 + tn * 128 + c;
    const size_t dbase = ((size_t)(tn * 32 + kb)) * 4096 + c * 8;
#pragma unroll
    for (int o = 0; o < 2; ++o) {
        ushx8 hv, lv;
#pragma unroll
        for (int q = 0; q < 8; ++q) {
            float v = src[(size_t)(o * 8 + q) * 4096];
            unsigned short h = f2bf(v);
            hv[q] = h; lv[q] = f2bf(v - bf2f(h));
        }
        int kq = ko * 2 + o;
        *(ushx8*)(WiHi + dbase + kq * 1024) = hv;
        *(ushx8*)(WiLo + dbase + kq * 1024) = lv;
    }
}

// ---------------------------------------------------------------------------
// Pass 1: G2 = x @ Wi + bias, split-bf16 MFMA, 128x128 tile, BK=32, 4 waves.
// ---------------------------------------------------------------------------
__global__ __launch_bounds__(256)
void xwi_gemm_mfma(const float* __restrict__ x,
                   const unsigned short* __restrict__ WiHi,
                   const unsigned short* __restrict__ WiLo,
                   const float* __restrict__ bias,
                   unsigned short* __restrict__ G2)
{
    __shared__ __align__(16) unsigned short AHi[4096], ALo[4096];
    __shared__ __align__(16) unsigned short BHi[4096], BLo[4096];
    const int bid = blockIdx.x;
    const int bm = bid >> 5, bn = bid & 31;
    const int m0 = bm << 7, n0 = bn << 7;
    const int t = threadIdx.x;
    const int w = t >> 6, l = t & 63, lq = l >> 4, lc = l & 15;
    const int wm = w >> 1, wn = w & 1;

    f32x4 acc[4][4] = {};
    const int row = t >> 1, kh = t & 1;
    const float* xrow = x + (size_t)(m0 + row) * 1024 + kh * 16;
    const unsigned short* bHsl = WiHi + (size_t)(bn * 32) * 4096;
    const unsigned short* bLsl = WiLo + (size_t)(bn * 32) * 4096;

    for (int kb = 0; kb < 32; ++kb) {
        float4 f0 = *(const float4*)(xrow + kb * 32 + 0);
        float4 f1 = *(const float4*)(xrow + kb * 32 + 4);
        float4 f2 = *(const float4*)(xrow + kb * 32 + 8);
        float4 f3 = *(const float4*)(xrow + kb * 32 + 12);
        float fs[16] = {f0.x, f0.y, f0.z, f0.w, f1.x, f1.y, f1.z, f1.w,
                        f2.x, f2.y, f2.z, f2.w, f3.x, f3.y, f3.z, f3.w};
#pragma unroll
        for (int o = 0; o < 2; ++o) {
            ushx8 hv, lv;
#pragma unroll
            for (int q = 0; q < 8; ++q) {
                float v = fs[o * 8 + q];
                unsigned short h = f2bf(v);
                hv[q] = h; lv[q] = f2bf(v - bf2f(h));
            }
            int kq = kh * 2 + o;
            *(ushx8*)&AHi[kq * 1024 + row * 8] = hv;
            *(ushx8*)&ALo[kq * 1024 + row * 8] = lv;
        }
        {
            const unsigned short* sH = bHsl + (size_t)kb * 4096;
            const unsigned short* sL = bLsl + (size_t)kb * 4096;
            gl_lds16(sH + (size_t)(w * 128 + l) * 8,      &BHi[(w * 128) * 8]);
            gl_lds16(sH + (size_t)(w * 128 + 64 + l) * 8, &BHi[(w * 128 + 64) * 8]);
            gl_lds16(sL + (size_t)(w * 128 + l) * 8,      &BLo[(w * 128) * 8]);
            gl_lds16(sL + (size_t)(w * 128 + 64 + l) * 8, &BLo[(w * 128 + 64) * 8]);
        }
        __syncthreads();

        bf16x8 xh[4], xl[4], wh_[4], wl_[4];
#pragma unroll
        for (int a = 0; a < 4; ++a) {
            int off = lq * 1024 + (wm * 64 + a * 16 + lc) * 8;
            xh[a] = *(const bf16x8*)&AHi[off];
            xl[a] = *(const bf16x8*)&ALo[off];
        }
#pragma unroll
        for (int b = 0; b < 4; ++b) {
            int off = lq * 1024 + (wn * 64 + b * 16 + lc) * 8;
            wh_[b] = *(const bf16x8*)&BHi[off];
            wl_[b] = *(const bf16x8*)&BLo[off];
        }
#pragma unroll
        for (int a = 0; a < 4; ++a)
#pragma unroll
            for (int b = 0; b < 4; ++b) {
                acc[a][b] = __builtin_amdgcn_mfma_f32_16x16x32_bf16(wh_[b], xh[a], acc[a][b], 0, 0, 0);
                acc[a][b] = __builtin_amdgcn_mfma_f32_16x16x32_bf16(wl_[b], xh[a], acc[a][b], 0, 0, 0);
                acc[a][b] = __builtin_amdgcn_mfma_f32_16x16x32_bf16(wh_[b], xl[a], acc[a][b], 0, 0, 0);
            }
        __syncthreads();
    }

    float bv[4][4];
#pragma unroll
    for (int b = 0; b < 4; ++b)
#pragma unroll
        for (int r = 0; r < 4; ++r)
            bv[b][r] = bias[n0 + wn * 64 + b * 16 + lq * 4 + r];
#pragma unroll
    for (int a = 0; a < 4; ++a) {
        int m = m0 + wm * 64 + a * 16 + lc;
        int step = m >> 6, b_el = m & 63;
#pragma unroll
        for (int b = 0; b < 4; ++b) {
            int j_abs = n0 + wn * 64 + b * 16 + lq * 4;
            int gate = j_abs >> 10;
            int wg_t = (j_abs & 1023) >> 2;
            ushx4 sv;
#pragma unroll
            for (int r = 0; r < 4; ++r) sv[r] = f2bf(acc[a][b][r] + bv[b][r]);
            *(ushx4*)(G2 + (((size_t)(step * 256 + wg_t) * 4 + gate) * 256 + b_el * 4)) = sv;
        }
    }
}

// ---------------------------------------------------------------------------
// Pass 2: cooperative MFMA scan. 256 WGs x 256 threads (4 waves), 4 units/WG.
// Round-5 verified barrier (spread flags, all-thread poll); hi-only h.
// ---------------------------------------------------------------------------
__global__ __launch_bounds__(256, 1)
void lstm_scan_mfma(const unsigned short* __restrict__ G2,
                    const float* __restrict__ Wh,
                    const float* __restrict__ h0, const float* __restrict__ c0,
                    float* __restrict__ out,
                    unsigned int* __restrict__ hp0,
                    unsigned int* __restrict__ hp1,
                    unsigned int* __restrict__ flags)
{
    __shared__ __align__(16) unsigned short WhHiS[16384];  // 32 KB
    __shared__ __align__(16) unsigned short WhLoS[16384];  // 32 KB
    __shared__ float zS[64 * 20];

    const int t  = threadIdx.x;
    const int wg = blockIdx.x;           // 0..255
    const int w  = t >> 6;
    const int l  = t & 63;
    const int lq = l >> 4, lc = l & 15;

    // Wh slice -> LDS (once): 16 z-cols, hi/lo split, B-fragment order
    for (int idx = t; idx < 16384; idx += 256) {
        int k = idx >> 4, c = idx & 15;
        int gcol = (c >> 2) * 1024 + wg * 4 + (c & 3);
        float wv = Wh[(size_t)k * 4096 + gcol];
        unsigned short hi = f2bf(wv);
        unsigned short lo = f2bf(wv - bf2f(hi));
        int pos = (((k >> 5) * 64) + (((k >> 3) & 3) * 16 + c)) * 8 + (k & 7);
        WhHiS[pos] = hi; WhLoS[pos] = lo;
    }

    // init hpack buffer 0 from h0 (bf16 hi only, sc1 -> IF$)
    {
        int idx = wg * 256 + t;
        if (idx < 32768) {
            int b = idx >> 9, k = (idx & 511) * 2;
            unsigned short h0s = f2bf(h0[b * 1024 + k]);
            unsigned short h1s = f2bf(h0[b * 1024 + k + 1]);
            int p32 = ((k >> 3) * 64 + b) * 4 + ((k & 7) >> 1);
            __hip_atomic_store(hp0 + p32, (unsigned int)h0s | ((unsigned int)h1s << 16),
                               __ATOMIC_RELAXED, __HIP_MEMORY_SCOPE_AGENT);
        }
    }

    const int b_el = t >> 2, u_el = t & 3;
    const int j = wg * 4 + u_el;
    float c_state = c0[b_el * 1024 + j];

    // initial barrier (round-5 form)
    {
        asm volatile("s_waitcnt vmcnt(0)" ::: "memory");
        __syncthreads();
        if (t == 0)
            __hip_atomic_store(&flags[wg * 32], 1u, __ATOMIC_RELAXED,
                               __HIP_MEMORY_SCOPE_AGENT);
        while (__hip_atomic_load(&flags[t * 32], __ATOMIC_RELAXED,
                                 __HIP_MEMORY_SCOPE_AGENT) < 1u) {}
        __syncthreads();
        asm volatile("" ::: "memory");
    }

    const int arow = (w << 4) + lc;
    for (int step = 0; step < 512; ++step) {
        const unsigned long long* hH =
            (const unsigned long long*)((step & 1) ? hp1 : hp0);
        unsigned int* nH = (step & 1) ? hp0 : hp1;

        // G prefetch: contiguous 2KB/WG panel, 4 x 2B per thread (dense)
        size_t pb = ((size_t)(step * 256 + wg) * 4) * 256 + t;
        unsigned short gvi = G2[pb];
        unsigned short gvf = G2[pb + 256];
        unsigned short gvg = G2[pb + 512];
        unsigned short gvo = G2[pb + 768];

        f32x4 acc0 = {0.f, 0.f, 0.f, 0.f};
        f32x4 acc2 = {0.f, 0.f, 0.f, 0.f};

        // software-pipelined K loop: 4 groups of 8 kb, double-buffered regs
        bf16x8 ah[2][8];
#pragma unroll
        for (int i = 0; i < 8; ++i) {
            int a64 = ((i * 4 + lq) * 64 + arow) * 2;
            ah[0][i] = ld_h16(hH + a64);
        }
#pragma unroll
        for (int g4 = 0; g4 < 4; ++g4) {
            if (g4 < 3) {
#pragma unroll
                for (int i = 0; i < 8; ++i) {
                    int kb = (g4 + 1) * 8 + i;
                    int a64 = ((kb * 4 + lq) * 64 + arow) * 2;
                    ah[(g4 + 1) & 1][i] = ld_h16(hH + a64);
                }
            }
#pragma unroll
            for (int i = 0; i < 8; ++i) {
                int kb = g4 * 8 + i;
                int bpos = (kb * 64 + l) * 8;
                bf16x8 bh = *(const bf16x8*)&WhHiS[bpos];
                bf16x8 bl = *(const bf16x8*)&WhLoS[bpos];
                bf16x8 a_h = ah[g4 & 1][i];
                acc0 = __builtin_amdgcn_mfma_f32_16x16x32_bf16(a_h, bh, acc0, 0, 0, 0);
                acc2 = __builtin_amdgcn_mfma_f32_16x16x32_bf16(a_h, bl, acc2, 0, 0, 0);
            }
        }

        // z tile -> LDS transpose (stride 20: <=2-way banks, free)
#pragma unroll
        for (int r = 0; r < 4; ++r)
            zS[(w * 16 + lq * 4 + r) * 20 + lc] = acc0[r] + acc2[r];
        __syncthreads();

        float zi = bf2f(gvi) + zS[b_el * 20 + u_el];
        float zf = bf2f(gvf) + zS[b_el * 20 + 4 + u_el];
        float zg = bf2f(gvg) + zS[b_el * 20 + 8 + u_el];
        float zo = bf2f(gvo) + zS[b_el * 20 + 12 + u_el];

        float ig = sigm_fast(zi);
        float fg = sigm_fast(zf);
        float gg = tanh_fast(zg);
        float og = sigm_fast(zo);

        c_state = fg * c_state + ig * gg;
        float nh = og * tanh_fast(c_state);

        if (step == 511) {
            out[(size_t)step * 65536 + b_el * 1024 + j] = nh;
            break;                      // no publish/barrier needed
        }

        // publish h (bf16 hi only, sc1 -> IF$, packed pairs via shfl)
        unsigned int hiw = f2bf(nh);
        unsigned int hi_o = (unsigned int)__shfl_xor((int)hiw, 1);
        if ((t & 1) == 0) {
            int p32 = ((j >> 3) * 64 + b_el) * 4 + ((j & 7) >> 1);
            __hip_atomic_store(nH + p32, (hiw & 0xffffu) | (hi_o << 16),
                               __ATOMIC_RELAXED, __HIP_MEMORY_SCOPE_AGENT);
        }

        // barrier: arrive (publishes drained), deferred out store, poll
        asm volatile("s_waitcnt vmcnt(0)" ::: "memory");
        __syncthreads();
        unsigned int target = (unsigned int)(step + 2);
        if (t == 0)
            __hip_atomic_store(&flags[wg * 32], target, __ATOMIC_RELAXED,
                               __HIP_MEMORY_SCOPE_AGENT);
        out[(size_t)step * 65536 + b_el * 1024 + j] = nh;   // drains next step
        while (__hip_atomic_load(&flags[t * 32], __ATOMIC_RELAXED,
                                 __HIP_MEMORY_SCOPE_AGENT) < target) {}
        __syncthreads();
        asm volatile("" ::: "memory");
    }
}

// ---------------------------------------------------------------------------
extern "C" void kernel_launch(void* const* d_in, const int* in_sizes, int n_in,
                              void* d_out, int out_size, void* d_ws, size_t ws_size,
                              hipStream_t stream)
{
    const float* x  = (const float*)d_in[0];
    const float* h0 = (const float*)d_in[1];
    const float* c0 = (const float*)d_in[2];
    const float* Wi = (const float*)d_in[3];
    const float* Wh = (const float*)d_in[4];
    const float* bb = (const float*)d_in[5];
    float* out = (float*)d_out;

    // ws layout: hp0/hp1 (128KB each) | flags 32KB | WiHi 8MB | WiLo 8MB | G2 268MB
    unsigned int* hp0 = (unsigned int*)d_ws;
    unsigned int* hp1 = hp0 + 32768;
    unsigned int* flags = hp1 + 32768;          // 256 * 32 u32 = 32KB
    unsigned short* WiHi = (unsigned short*)(flags + 8192);
    unsigned short* WiLo = WiHi + 4194304;
    unsigned short* G2 = WiLo + 4194304;

    hipMemsetAsync(flags, 0, 8192 * sizeof(unsigned int), stream);
    wi_pack<<<dim3(1024), dim3(256), 0, stream>>>(Wi, WiHi, WiLo);
    xwi_gemm_mfma<<<dim3(8192), dim3(256), 0, stream>>>(x, WiHi, WiLo, bb, G2);

    void* args[] = {(void*)&G2, (void*)&Wh, (void*)&h0, (void*)&c0, (void*)&out,
                    (void*)&hp0, (void*)&hp1, (void*)&flags};
    hipLaunchCooperativeKernel(reinterpret_cast<void*>(&lstm_scan_mfma),
                               dim3(256), dim3(256), args, 0, stream);
}